// Round 4
// baseline (150.499 us; speedup 1.0000x reference)
//
#include <hip/hip_runtime.h>
#include <math.h>

#define NQ 12
#define NL 4
#define NA 6
#define BATCH 4096
#define NT 256
#define RSTR 17   // row stride (f2 for T_b view, float for T_a view); odd -> conflict-free floors

typedef float f2 __attribute__((ext_vector_type(2)));

// HW-verified (R3-R10) packed complex primitives; (re,im) in a VGPR pair.
#define CMUL(d, u, a)  asm("v_pk_mul_f32 %0, %1, %2 op_sel_hi:[0,1]"                 : "=v"(d) : "v"(u), "v"(a))
#define CMACR(d, u, a) asm("v_pk_fma_f32 %0, %1, %2, %0 op_sel_hi:[0,1,1]"           : "+v"(d) : "v"(u), "v"(a))
#define CMACI(d, u, a) asm("v_pk_fma_f32 %0, %1, %2, %0 op_sel:[1,1,0] op_sel_hi:[1,0,1] neg_lo:[1,0,0]" : "+v"(d) : "v"(u), "v"(a))
// R10-verified scalar-broadcast variants (coefficient f2 = (c,s)):
#define RYMULS(d, u, a)  asm("v_pk_mul_f32 %0, %1, %2 op_sel:[1,0] op_sel_hi:[1,1]"  : "=v"(d) : "v"(u), "v"(a))
#define RYMACNS(d, u, a) asm("v_pk_fma_f32 %0, %1, %2, %0 op_sel:[1,0,0] op_sel_hi:[1,1,1] neg_lo:[1,0,0] neg_hi:[1,0,0]" : "+v"(d) : "v"(u), "v"(a))
#define WFENCE() asm volatile("s_waitcnt lgkmcnt(0)" ::: "memory")

// Real RY butterfly: n0 = c*a0 - s*a1 ; n1 = s*a0 + c*a1   (4 pk ops)
#define RYBFLY(A0, A1, CS) do { \
    f2 _a0 = (A0), _a1 = (A1), _n0, _n1; \
    CMUL  (_n0, CS, _a0); RYMACNS(_n0, CS, _a1); \
    RYMULS(_n1, CS, _a0); CMACR  (_n1, CS, _a1); \
    (A0) = _n0; (A1) = _n1; } while (0)

#define RYGATE(gidx, bq) do { \
    const f2 cs = *(const f2*)(rots + (gidx) * 2); \
    const int S = 1 << (bq); \
    _Pragma("unroll") \
    for (int m = 0; m < 8; ++m) { \
        const int j0 = ((m & ~(S - 1)) << 1) | (m & (S - 1)); \
        RYBFLY(st[j0], st[j0 + S], cs); \
    } } while (0)

// Circuit algebra (R10-verified): Rot = RZ(omega)*RY(theta)*RZ(phi); diagonals folded:
// RZ(phi_0) into init; D_l = RZ(omega_l)*CZ*RZ(phi_{l+1}) between RY layers; trailing
// RZ(omega_3)+CZ_3 dropped (probs phase-invariant).
// Layouts (R8-verified): L1: i=(lam5..lam0,w1,w0,j3..j0); L2: i=(lam5,lam4,j3..j0,w1,w0,lam3..0);
// L3: i=(j3,j2,lam5,lam4,w1,w0,j1,j0,lam3..0).
// T_a (L1<->L2, involution, wave-local, b32 re/im passes over float[256][17]) — R12-verified.
// R14 T_b (L2<->L3, involution, cross-wave): b64 row-split two-pass over f2[128][17] (same
//   17408 B). R13 post-mortem found 3 bugs, all fixed here:
//   (1) pass-B rows PHYSICALLY ALIAS pass-A rows (128-row buffer) -> conservative 4-barrier
//       schedule: bar / passA writes (w<2) / bar / phase2 reads (j&2)==0 / bar / passB writes
//       (w>=2) / bar / phase3 reads (j&2)!=0. No barrier elision inside T_b.
//   (2) involution cross-pairs: phase-2 reads clobber waves 2,3's (j&2)==0 ORIGINALS, which
//       phase-3 readers need from pass-B rows -> waves 2,3 save those 8 f2 in temps before
//       phase-2 and stage pass B from temps.
//   (3) Walsh signs: part[q]=bit?-tot:+tot -> spawn D = S - p (low minus high);
//       qout[6]=S0+S1-S2-S3 (w1 set for w>=2), qout[7]=S0-S1+S2-S3 (w0 set for odd w).
//   Bank floors: writes dw=(34*row+2j), reads dw=(34*ROWL+2*col_b) -> 16 even residues x4
//   lanes = R10-verified b64 pattern (free 2-way per m136).
// R14 epilogue: Walsh-trick reduction — reduce tot once spawning the six single-bit diffs
//   D5..D0 (21 shfl) + 4 plain reductions m8..m11 (24 shfl) = 45 shfl vs 72.
// d_ws float layout: [0..95] 48 gates (c,s) | [96..143] alphas[4][12] | [144..271] dreg[4][16] (re,im)

__global__ void setup_kernel(const float* __restrict__ weights, float* __restrict__ ws) {
    const int t = threadIdx.x;   // 64 threads
    if (t < NL * NQ) {
        const float th = weights[t * 3 + 1];
        float s, c;
        sincosf(0.5f * th, &s, &c);
        ws[t * 2 + 0] = c; ws[t * 2 + 1] = s;
        const int r = t / NQ, q = t % NQ;
        float a;
        if (r == 0) a = 0.5f * weights[q * 3 + 0];
        else        a = 0.5f * (weights[((r - 1) * NQ + q) * 3 + 2] +
                                 weights[(r * NQ + q) * 3 + 0]);
        ws[96 + t] = a;
    }
    {
        const int d = t >> 4, j = t & 15;
        int wq[4];
        if (d == 1 || d == 3) { wq[0] = 0; wq[1] = 1; wq[2] = 6; wq[3] = 7; }
        else                  { wq[0] = 8; wq[1] = 9; wq[2] = 10; wq[3] = 11; }
        float g = 0.0f;
#pragma unroll
        for (int k = 0; k < 4; ++k) {
            const int q = wq[k];
            const float a = (d == 0) ? 0.5f * weights[q * 3 + 0]
                                     : 0.5f * (weights[((d - 1) * NQ + q) * 3 + 2] +
                                               weights[(d * NQ + q) * 3 + 0]);
            g += ((j >> (3 - k)) & 1) ? a : -a;
        }
        float sg, cg;
        sincosf(g, &sg, &cg);
        ws[144 + (d * 16 + j) * 2 + 0] = cg;
        ws[144 + (d * 16 + j) * 2 + 1] = sg;
    }
}

// st[j] *= (cos b, sin b) * dreg_tab[j]   (R10-verified)
__device__ __forceinline__ void apply_phase(f2* st, const float* tab, float beta) {
    float sb, cb;
    sincosf(beta, &sb, &cb);
    const f2 Dth = (f2){cb, sb};
#pragma unroll
    for (int j = 0; j < 16; ++j) {
        const f2 a = st[j];
        f2 t, u;
        CMUL(t, Dth, a); CMACI(t, Dth, a);
        const f2 dg = *(const f2*)(tab + 2 * j);
        CMUL(u, dg, t); CMACI(u, dg, t);
        st[j] = u;
    }
}

__global__ __launch_bounds__(NT) void qdqn_kernel(
    const float* __restrict__ x,       // [BATCH,12]
    const float* __restrict__ rots,    // d_ws tables
    const float* __restrict__ fc_w,    // [6,12]
    const float* __restrict__ fc_b,    // [6]
    float* __restrict__ out)           // [BATCH,6]
{
    // 17408 B dual-view transpose buffer: float[256][17] (T_a, b32) == f2[128][17] (T_b, b64)
    __shared__ __align__(16) f2 buf2[128 * RSTR];
    float* const bufr = (float*)buf2;
    __shared__ float encc[NQ], encs[NQ];
    __shared__ float red[4][NQ];
    __shared__ float qout[NQ];

    const int tix = threadIdx.x;
    const int lam = tix & 63;
    const int w   = tix >> 6;
    const int w1  = (w >> 1) & 1, w0 = w & 1;
    const int b   = blockIdx.x;

    const float* alph = rots + 96;
    const float* dreg = rots + 144;

    if (tix < NQ) {
        float s, c;
        sincosf(0.5f * x[b * NQ + tix], &s, &c);
        encc[tix] = c; encs[tix] = s;
    }
    __syncthreads();

    // --- RY product state in L1 (real) ---
    f2 st[16];
    {
        float pre = 1.0f;
#pragma unroll
        for (int q = 0; q < 6; ++q)
            pre *= ((lam >> (5 - q)) & 1) ? encs[q] : encc[q];
        pre *= w1 ? encs[6] : encc[6];
        pre *= w0 ? encs[7] : encc[7];
        const float c8 = encc[8],  s8 = encs[8];
        const float c9 = encc[9],  s9 = encs[9];
        const float cA = encc[10], sA = encs[10];
        const float cB = encc[11], sB = encs[11];
#pragma unroll
        for (int j = 0; j < 16; ++j) {
            float v = pre;
            v *= (j & 8) ? s8 : c8;
            v *= (j & 4) ? s9 : c9;
            v *= (j & 2) ? sA : cA;
            v *= (j & 1) ? sB : cB;
            st[j] = (f2){ v, 0.0f };
        }
    }

#define BETA_L1(al) ( (((lam >> 5) & 1) ? (al)[0] : -(al)[0]) + (((lam >> 4) & 1) ? (al)[1] : -(al)[1]) \
                    + (((lam >> 3) & 1) ? (al)[2] : -(al)[2]) + (((lam >> 2) & 1) ? (al)[3] : -(al)[3]) \
                    + (((lam >> 1) & 1) ? (al)[4] : -(al)[4]) + (((lam >> 0) & 1) ? (al)[5] : -(al)[5]) \
                    + (w1 ? (al)[6] : -(al)[6]) + (w0 ? (al)[7] : -(al)[7]) )
#define BETA_L3(al) ( (((lam >> 5) & 1) ? (al)[2] : -(al)[2]) + (((lam >> 4) & 1) ? (al)[3] : -(al)[3]) \
                    + (w1 ? (al)[4] : -(al)[4]) + (w0 ? (al)[5] : -(al)[5]) \
                    + (((lam >> 3) & 1) ? (al)[8] : -(al)[8]) + (((lam >> 2) & 1) ? (al)[9] : -(al)[9]) \
                    + (((lam >> 1) & 1) ? (al)[10] : -(al)[10]) + (((lam >> 0) & 1) ? (al)[11] : -(al)[11]) )

    // --- init diagonal: RZ(phi_0) in L1 ---
    apply_phase(st, dreg + 0 * 32, BETA_L1(alph + 0 * NQ));

    const int col_b = ((lam >> 4) << 2) | w;
    const int row_a = (w << 6) | (lam & 0x30);
    const int col_a = lam & 0xF;
    const int lam15 = lam & 15;

    // T_a (wave-local throughout: wave w only touches float-rows (w<<6)..(w<<6)+63): fences only.
#define TRANSPOSE_A_FWD() do { \
    WFENCE(); \
    _Pragma("unroll") for (int j = 0; j < 16; ++j) bufr[tix * RSTR + j] = st[j].x; \
    WFENCE(); \
    _Pragma("unroll") for (int j = 0; j < 16; ++j) st[j].x = bufr[(row_a + j) * RSTR + col_a]; \
    WFENCE(); \
    _Pragma("unroll") for (int j = 0; j < 16; ++j) bufr[tix * RSTR + j] = st[j].y; \
    WFENCE(); \
    _Pragma("unroll") for (int j = 0; j < 16; ++j) st[j].y = bufr[(row_a + j) * RSTR + col_a]; \
    } while (0)

    // local row for both T_b read phases ((j&3)==(j&1) when (j&2)==0; TBROW-128 when (j&2)!=0)
#define TB_ROWL(j) (((((j) & 1) << 6) | (((j) >> 2) << 4) | lam15) * RSTR + col_b)

    // T_b b64 row-split two-pass (R14, conservative 4-barrier schedule; see header comment)
#define TB_FULL() do { \
    f2 t0, t1, t2, t3, t4, t5, t6, t7; \
    if (w >= 2) { t0 = st[0]; t1 = st[1]; t2 = st[4];  t3 = st[5]; \
                  t4 = st[8]; t5 = st[9]; t6 = st[12]; t7 = st[13]; } \
    __syncthreads();                 /* prior readers of buf drained */ \
    if (w < 2) { _Pragma("unroll") for (int j = 0; j < 16; ++j) \
        buf2[(tix & 127) * RSTR + j] = st[j]; } \
    __syncthreads();                 /* pass-A rows visible */ \
    _Pragma("unroll") for (int j = 0; j < 16; ++j) if ((j & 2) == 0) \
        st[j] = buf2[TB_ROWL(j)]; \
    __syncthreads();                 /* phase-2 reads drained before overwrite */ \
    if (w >= 2) { \
        const int r = (tix & 127) * RSTR; \
        buf2[r + 0]  = t0;     buf2[r + 1]  = t1;     buf2[r + 2]  = st[2];  buf2[r + 3]  = st[3]; \
        buf2[r + 4]  = t2;     buf2[r + 5]  = t3;     buf2[r + 6]  = st[6];  buf2[r + 7]  = st[7]; \
        buf2[r + 8]  = t4;     buf2[r + 9]  = t5;     buf2[r + 10] = st[10]; buf2[r + 11] = st[11]; \
        buf2[r + 12] = t6;     buf2[r + 13] = t7;     buf2[r + 14] = st[14]; buf2[r + 15] = st[15]; \
    } \
    __syncthreads();                 /* pass-B rows visible */ \
    _Pragma("unroll") for (int j = 0; j < 16; ++j) if ((j & 2) != 0) \
        st[j] = buf2[TB_ROWL(j)]; \
    } while (0)

#pragma unroll 1
    for (int h = 0; h < 2; ++h) {
        // ============ forward layer l = 2h : L1 -> L2 -> L3 ============
        {
            const int gb = (2 * h) * NQ;
            RYGATE(gb + 11, 0); RYGATE(gb + 10, 1); RYGATE(gb + 9, 2); RYGATE(gb + 8, 3);
            TRANSPOSE_A_FWD();                      // wave-local (prior readers in-wave or none)
            RYGATE(gb + 5, 0); RYGATE(gb + 4, 1); RYGATE(gb + 3, 2); RYGATE(gb + 2, 3);
            TB_FULL();                              // L2 -> L3
            RYGATE(gb + 7, 0); RYGATE(gb + 6, 1); RYGATE(gb + 1, 2); RYGATE(gb + 0, 3);
            // CZ sign in L3 (R8-verified)
            {
                const int l5 = (lam >> 5) & 1, l4 = (lam >> 4) & 1, l3 = (lam >> 3) & 1;
                const int par = (l5 & l4) + (l4 & w1) + (w1 & w0) + __popc(lam & (lam >> 1) & 0x7);
                const float base = (par & 1) ? -1.0f : 1.0f;
                const float fA = l5 ? -1.0f : 1.0f;
                const float fB = w0 ? -1.0f : 1.0f;
                const float fC = l3 ? -1.0f : 1.0f;
#pragma unroll
                for (int j = 0; j < 16; ++j) {
                    float s = base;
                    if (j & 4) s *= fA;
                    if (j & 2) s *= fB;
                    if (j & 1) s *= fC;
                    if ((((j & 12) == 12) ? 1 : 0) ^ (((j & 3) == 3) ? 1 : 0)) s = -s;
                    st[j] *= s;
                }
            }
            // fused RZ diagonal, row 2h+1, in L3
            apply_phase(st, dreg + (2 * h + 1) * 32, BETA_L3(alph + (2 * h + 1) * NQ));
        }
        // ============ reverse layer l = 2h+1 : L3 -> L2 -> L1 ============
        {
            const int gb = (2 * h + 1) * NQ;
            RYGATE(gb + 7, 0); RYGATE(gb + 6, 1); RYGATE(gb + 1, 2); RYGATE(gb + 0, 3);
            TB_FULL();                              // L3 -> L2 (leading barrier inside macro)
            RYGATE(gb + 5, 0); RYGATE(gb + 4, 1); RYGATE(gb + 3, 2); RYGATE(gb + 2, 3);
            // T_a back (prior T_b phase-3 reads cross-wave -> barrier before writes)
            __syncthreads();
#pragma unroll
            for (int j = 0; j < 16; ++j) bufr[tix * RSTR + j] = st[j].x;
            WFENCE();
#pragma unroll
            for (int j = 0; j < 16; ++j) st[j].x = bufr[(row_a + j) * RSTR + col_a];
            WFENCE();
#pragma unroll
            for (int j = 0; j < 16; ++j) bufr[tix * RSTR + j] = st[j].y;
            WFENCE();
#pragma unroll
            for (int j = 0; j < 16; ++j) st[j].y = bufr[(row_a + j) * RSTR + col_a];
            RYGATE(gb + 11, 0); RYGATE(gb + 10, 1); RYGATE(gb + 9, 2); RYGATE(gb + 8, 3);
            if (h == 0) {
                // CZ sign in L1 (R6/R8-verified)
                {
                    const int par = __popc(lam & (lam >> 1)) + ((lam & 1) & w1) + (w1 & w0);
                    const float base = (par & 1) ? -1.0f : 1.0f;
                    const float sHi = w0 ? -base : base;
#pragma unroll
                    for (int j = 0; j < 16; ++j) {
                        float s = (j & 8) ? sHi : base;
                        if (__popc(j & (j >> 1)) & 1) s = -s;
                        st[j] *= s;
                    }
                }
                // fused RZ diagonal, row 2, in L1
                apply_phase(st, dreg + 2 * 32, BETA_L1(alph + 2 * NQ));
            }
            // h==1: trailing diagonals dropped (probs phase-invariant)
        }
    }

    // --- measurement in L1 ---
    float tot = 0.f, m8 = 0.f, m9 = 0.f, m10 = 0.f, m11 = 0.f;
#pragma unroll
    for (int j = 0; j < 16; ++j) {
        const float p = st[j].x * st[j].x + st[j].y * st[j].y;
        tot += p;
        m8  += (j & 8) ? -p : p;
        m9  += (j & 4) ? -p : p;
        m10 += (j & 2) ? -p : p;
        m11 += (j & 1) ? -p : p;
    }

    // Walsh reduction of tot over the 6 lane bits (signs R14-corrected):
    // part[q] = (lam bit (5-q)) ? -tot : +tot  ->  D = S - p at spawn (low half minus high half).
    float S = tot, D5, D4, D3, D2, D1, D0, p;
    p = __shfl_down(S, 32, 64); D5 = S - p; S += p;
    p = __shfl_down(S, 16, 64); D4 = S - p; S += p;
    D5 += __shfl_down(D5, 16, 64);
    p = __shfl_down(S, 8, 64);  D3 = S - p; S += p;
    D5 += __shfl_down(D5, 8, 64); D4 += __shfl_down(D4, 8, 64);
    p = __shfl_down(S, 4, 64);  D2 = S - p; S += p;
    D5 += __shfl_down(D5, 4, 64); D4 += __shfl_down(D4, 4, 64); D3 += __shfl_down(D3, 4, 64);
    p = __shfl_down(S, 2, 64);  D1 = S - p; S += p;
    D5 += __shfl_down(D5, 2, 64); D4 += __shfl_down(D4, 2, 64); D3 += __shfl_down(D3, 2, 64);
    D2 += __shfl_down(D2, 2, 64);
    p = __shfl_down(S, 1, 64);  D0 = S - p; S += p;
    D5 += __shfl_down(D5, 1, 64); D4 += __shfl_down(D4, 1, 64); D3 += __shfl_down(D3, 1, 64);
    D2 += __shfl_down(D2, 1, 64); D1 += __shfl_down(D1, 1, 64);
#pragma unroll
    for (int off = 32; off > 0; off >>= 1) {
        m8  += __shfl_down(m8,  off, 64);
        m9  += __shfl_down(m9,  off, 64);
        m10 += __shfl_down(m10, off, 64);
        m11 += __shfl_down(m11, off, 64);
    }

    if (lam == 0) {
        red[w][0] = D5; red[w][1] = D4; red[w][2] = D3;
        red[w][3] = D2; red[w][4] = D1; red[w][5] = D0;
        red[w][6] = S;
        red[w][7] = m8; red[w][8] = m9; red[w][9] = m10; red[w][10] = m11;
    }
    __syncthreads();
    if (tix < NQ) {
        float v;
        if (tix < 6)       v = red[0][tix] + red[1][tix] + red[2][tix] + red[3][tix];
        else if (tix == 6) v = red[0][6] + red[1][6] - red[2][6] - red[3][6];  // w1 set for w>=2
        else if (tix == 7) v = red[0][6] - red[1][6] + red[2][6] - red[3][6];  // w0 set for odd w
        else { const int k = tix - 1; v = red[0][k] + red[1][k] + red[2][k] + red[3][k]; }
        qout[tix] = v;
    }
    __syncthreads();

    if (tix < NA) {
        float acc = fc_b[tix];
#pragma unroll
        for (int q = 0; q < NQ; ++q)
            acc += qout[q] * fc_w[tix * NQ + q];
        out[b * NA + tix] = acc;
    }
}

extern "C" void kernel_launch(void* const* d_in, const int* in_sizes, int n_in,
                              void* d_out, int out_size, void* d_ws, size_t ws_size,
                              hipStream_t stream) {
    const float* x   = (const float*)d_in[0];
    const float* wts = (const float*)d_in[1];
    const float* fcw = (const float*)d_in[2];
    const float* fcb = (const float*)d_in[3];
    float* tabs = (float*)d_ws;   // 272 f32 = 1088 B
    setup_kernel<<<1, 64, 0, stream>>>(wts, tabs);
    qdqn_kernel<<<BATCH, NT, 0, stream>>>(x, tabs, fcw, fcb, (float*)d_out);
}

// Round 5
// 148.050 us; speedup vs baseline: 1.0165x; 1.0165x over previous
//
#include <hip/hip_runtime.h>
#include <math.h>

#define NQ 12
#define NL 4
#define NA 6
#define BATCH 4096
#define NT 256
#define RSTR 17   // float (b32) row stride; odd -> conflict-free at 2-dword/bank b32 floor

typedef float f2 __attribute__((ext_vector_type(2)));

// HW-verified (R3-R10) packed complex primitives; (re,im) in a VGPR pair.
#define CMUL(d, u, a)  asm("v_pk_mul_f32 %0, %1, %2 op_sel_hi:[0,1]"                 : "=v"(d) : "v"(u), "v"(a))
#define CMACR(d, u, a) asm("v_pk_fma_f32 %0, %1, %2, %0 op_sel_hi:[0,1,1]"           : "+v"(d) : "v"(u), "v"(a))
#define CMACI(d, u, a) asm("v_pk_fma_f32 %0, %1, %2, %0 op_sel:[1,1,0] op_sel_hi:[1,0,1] neg_lo:[1,0,0]" : "+v"(d) : "v"(u), "v"(a))
// R10-verified scalar-broadcast variants (coefficient f2 = (c,s)):
#define RYMULS(d, u, a)  asm("v_pk_mul_f32 %0, %1, %2 op_sel:[1,0] op_sel_hi:[1,1]"  : "=v"(d) : "v"(u), "v"(a))
#define RYMACNS(d, u, a) asm("v_pk_fma_f32 %0, %1, %2, %0 op_sel:[1,0,0] op_sel_hi:[1,1,1] neg_lo:[1,0,0] neg_hi:[1,0,0]" : "+v"(d) : "v"(u), "v"(a))
#define WFENCE() asm volatile("s_waitcnt lgkmcnt(0)" ::: "memory")

// Real RY butterfly: n0 = c*a0 - s*a1 ; n1 = s*a0 + c*a1   (4 pk ops)
#define RYBFLY(A0, A1, CS) do { \
    f2 _a0 = (A0), _a1 = (A1), _n0, _n1; \
    CMUL  (_n0, CS, _a0); RYMACNS(_n0, CS, _a1); \
    RYMULS(_n1, CS, _a0); CMACR  (_n1, CS, _a1); \
    (A0) = _n0; (A1) = _n1; } while (0)

#define RYGATE(gidx, bq) do { \
    const f2 cs = *(const f2*)(rots + (gidx) * 2); \
    const int S = 1 << (bq); \
    _Pragma("unroll") \
    for (int m = 0; m < 8; ++m) { \
        const int j0 = ((m & ~(S - 1)) << 1) | (m & (S - 1)); \
        RYBFLY(st[j0], st[j0 + S], cs); \
    } } while (0)

// Circuit algebra (R10-verified): Rot = RZ(omega)*RY(theta)*RZ(phi); diagonals folded:
// RZ(phi_0) into init; D_l = RZ(omega_l)*CZ*RZ(phi_{l+1}) between RY layers; trailing
// RZ(omega_3)+CZ_3 dropped (probs phase-invariant).
// Layouts (R8-verified): L1: i=(lam5..lam0,w1,w0,j3..j0); L2: i=(lam5,lam4,j3..j0,w1,w0,lam3..0);
// L3: i=(j3,j2,lam5,lam4,w1,w0,j1,j0,lam3..0).
// T_a (L1<->L2, involution, wave-local, b32 re/im passes over float[256][17]) — R12-verified.
// T_b (L2<->L3, involution, cross-wave, b32 re/im passes, 3-4 barriers) — R12-verified.
//   (R14 post-mortem: b64 T_b needs 16 VGPRs of temps -> crosses the 64-VGPR occupancy granule,
//    occupancy 46->29, net LOSS. b32 T_b at VGPR 48 is the keeper.)
// R15: (a) Walsh epilogue (R14-HW-verified signs): reduce tot once spawning the six single-bit
//   diffs D5..D0 (21 shfl) + plain m8..m11 (24 shfl) = 45 shfl vs 72; part[12] array deleted.
//   (b) beta-table: e^{i*beta(row,thread)} is batch-invariant -> precomputed in setup_kernel
//   (1024 f2 at ws[272..2319]); apply_phase takes (cb,sb) as an f2 loaded from the table,
//   deleting the 8-term conditional-add chain + sincosf (~45 instr) per call, x4 calls.
// d_ws float layout: [0..95] 48 gates (c,s) | [96..143] alphas[4][12] | [144..271] dreg[4][16]
//   (re,im) | [272..2319] beta table: (cos,sin) of beta_r(tix) for r=0..3, tix=0..255.
//   Rows r even use BETA_L1 form, r odd use BETA_L3 form (matching layout at application point).

__global__ void setup_kernel(const float* __restrict__ weights, float* __restrict__ ws) {
    __shared__ float alph_s[NL * NQ];
    const int t = threadIdx.x;   // 64 threads
    if (t < NL * NQ) {
        const float th = weights[t * 3 + 1];
        float s, c;
        sincosf(0.5f * th, &s, &c);
        ws[t * 2 + 0] = c; ws[t * 2 + 1] = s;
        const int r = t / NQ, q = t % NQ;
        float a;
        if (r == 0) a = 0.5f * weights[q * 3 + 0];
        else        a = 0.5f * (weights[((r - 1) * NQ + q) * 3 + 2] +
                                 weights[(r * NQ + q) * 3 + 0]);
        ws[96 + t] = a;
        alph_s[t] = a;
    }
    {
        const int d = t >> 4, j = t & 15;
        int wq[4];
        if (d == 1 || d == 3) { wq[0] = 0; wq[1] = 1; wq[2] = 6; wq[3] = 7; }
        else                  { wq[0] = 8; wq[1] = 9; wq[2] = 10; wq[3] = 11; }
        float g = 0.0f;
#pragma unroll
        for (int k = 0; k < 4; ++k) {
            const int q = wq[k];
            const float a = (d == 0) ? 0.5f * weights[q * 3 + 0]
                                     : 0.5f * (weights[((d - 1) * NQ + q) * 3 + 2] +
                                               weights[(d * NQ + q) * 3 + 0]);
            g += ((j >> (3 - k)) & 1) ? a : -a;
        }
        float sg, cg;
        sincosf(g, &sg, &cg);
        ws[144 + (d * 16 + j) * 2 + 0] = cg;
        ws[144 + (d * 16 + j) * 2 + 1] = sg;
    }
    __syncthreads();
    // beta table: 4 rows x 256 thread-positions; row even -> L1 form, row odd -> L3 form.
#pragma unroll 1
    for (int k = 0; k < 16; ++k) {
        const int i   = t * 16 + k;       // 0..1023
        const int r   = i >> 8;
        const int ti  = i & 255;
        const int lam = ti & 63, wv = ti >> 6;
        const int w1 = (wv >> 1) & 1, w0 = wv & 1;
        const float* al = alph_s + r * NQ;
        float beta;
        if ((r & 1) == 0) {   // BETA_L1
            beta = (((lam >> 5) & 1) ? al[0] : -al[0]) + (((lam >> 4) & 1) ? al[1] : -al[1])
                 + (((lam >> 3) & 1) ? al[2] : -al[2]) + (((lam >> 2) & 1) ? al[3] : -al[3])
                 + (((lam >> 1) & 1) ? al[4] : -al[4]) + (((lam >> 0) & 1) ? al[5] : -al[5])
                 + (w1 ? al[6] : -al[6]) + (w0 ? al[7] : -al[7]);
        } else {              // BETA_L3
            beta = (((lam >> 5) & 1) ? al[2] : -al[2]) + (((lam >> 4) & 1) ? al[3] : -al[3])
                 + (w1 ? al[4] : -al[4]) + (w0 ? al[5] : -al[5])
                 + (((lam >> 3) & 1) ? al[8] : -al[8]) + (((lam >> 2) & 1) ? al[9] : -al[9])
                 + (((lam >> 1) & 1) ? al[10] : -al[10]) + (((lam >> 0) & 1) ? al[11] : -al[11]);
        }
        float sb, cb;
        sincosf(beta, &sb, &cb);
        ws[272 + (r * 256 + ti) * 2 + 0] = cb;
        ws[272 + (r * 256 + ti) * 2 + 1] = sb;
    }
}

// st[j] *= Dth * dreg_tab[j]   (R10-verified core; R15: Dth from beta table)
__device__ __forceinline__ void apply_phase(f2* st, const float* tab, f2 Dth) {
#pragma unroll
    for (int j = 0; j < 16; ++j) {
        const f2 a = st[j];
        f2 t, u;
        CMUL(t, Dth, a); CMACI(t, Dth, a);
        const f2 dg = *(const f2*)(tab + 2 * j);
        CMUL(u, dg, t); CMACI(u, dg, t);
        st[j] = u;
    }
}

__global__ __launch_bounds__(NT) void qdqn_kernel(
    const float* __restrict__ x,       // [BATCH,12]
    const float* __restrict__ rots,    // d_ws tables
    const float* __restrict__ fc_w,    // [6,12]
    const float* __restrict__ fc_b,    // [6]
    float* __restrict__ out)           // [BATCH,6]
{
    __shared__ __align__(16) float bufr[NT * RSTR];   // 17408 B b32 transpose buffer
    __shared__ float encc[NQ], encs[NQ];
    __shared__ float red[4][NQ];
    __shared__ float qout[NQ];

    const int tix = threadIdx.x;
    const int lam = tix & 63;
    const int w   = tix >> 6;
    const int w1  = (w >> 1) & 1, w0 = w & 1;
    const int b   = blockIdx.x;

    const float* dreg = rots + 144;
    const float* btab = rots + 272;

    if (tix < NQ) {
        float s, c;
        sincosf(0.5f * x[b * NQ + tix], &s, &c);
        encc[tix] = c; encs[tix] = s;
    }
    __syncthreads();

    // --- RY product state in L1 (real) ---
    f2 st[16];
    {
        float pre = 1.0f;
#pragma unroll
        for (int q = 0; q < 6; ++q)
            pre *= ((lam >> (5 - q)) & 1) ? encs[q] : encc[q];
        pre *= w1 ? encs[6] : encc[6];
        pre *= w0 ? encs[7] : encc[7];
        const float c8 = encc[8],  s8 = encs[8];
        const float c9 = encc[9],  s9 = encs[9];
        const float cA = encc[10], sA = encs[10];
        const float cB = encc[11], sB = encs[11];
#pragma unroll
        for (int j = 0; j < 16; ++j) {
            float v = pre;
            v *= (j & 8) ? s8 : c8;
            v *= (j & 4) ? s9 : c9;
            v *= (j & 2) ? sA : cA;
            v *= (j & 1) ? sB : cB;
            st[j] = (f2){ v, 0.0f };
        }
    }

    // --- init diagonal: RZ(phi_0) in L1 (beta row 0) ---
    apply_phase(st, dreg + 0 * 32, *(const f2*)(btab + (0 * 256 + tix) * 2));

    const int col_b = ((lam >> 4) << 2) | w;
    const int row_a = (w << 6) | (lam & 0x30);
    const int col_a = lam & 0xF;

#define TBROW(j) ((((j) & 3) << 6) | (((j) >> 2) << 4) | (lam & 15))

    // T_a (wave-local throughout: wave w only touches float-rows (w<<6)..(w<<6)+63): fences only.
#define TRANSPOSE_A_FWD() do { \
    WFENCE(); \
    _Pragma("unroll") for (int j = 0; j < 16; ++j) bufr[tix * RSTR + j] = st[j].x; \
    WFENCE(); \
    _Pragma("unroll") for (int j = 0; j < 16; ++j) st[j].x = bufr[(row_a + j) * RSTR + col_a]; \
    WFENCE(); \
    _Pragma("unroll") for (int j = 0; j < 16; ++j) bufr[tix * RSTR + j] = st[j].y; \
    WFENCE(); \
    _Pragma("unroll") for (int j = 0; j < 16; ++j) st[j].y = bufr[(row_a + j) * RSTR + col_a]; \
    } while (0)

#pragma unroll 1
    for (int h = 0; h < 2; ++h) {
        // ============ forward layer l = 2h : L1 -> L2 -> L3 ============
        {
            const int gb = (2 * h) * NQ;
            RYGATE(gb + 11, 0); RYGATE(gb + 10, 1); RYGATE(gb + 9, 2); RYGATE(gb + 8, 3);
            TRANSPOSE_A_FWD();                      // wave-local (prior readers in-wave or none)
            RYGATE(gb + 5, 0); RYGATE(gb + 4, 1); RYGATE(gb + 3, 2); RYGATE(gb + 2, 3);
            // T_b (cross-wave reads), re pass then im pass (R12-verified schedule)
            WFENCE();
#pragma unroll
            for (int j = 0; j < 16; ++j) bufr[tix * RSTR + j] = st[j].x;
            __syncthreads();
#pragma unroll
            for (int j = 0; j < 16; ++j) st[j].x = bufr[TBROW(j) * RSTR + col_b];
            __syncthreads();   // drain re reads before im overwrites
#pragma unroll
            for (int j = 0; j < 16; ++j) bufr[tix * RSTR + j] = st[j].y;
            __syncthreads();
#pragma unroll
            for (int j = 0; j < 16; ++j) st[j].y = bufr[TBROW(j) * RSTR + col_b];
            RYGATE(gb + 7, 0); RYGATE(gb + 6, 1); RYGATE(gb + 1, 2); RYGATE(gb + 0, 3);
            // CZ sign in L3 (R8-verified)
            {
                const int l5 = (lam >> 5) & 1, l4 = (lam >> 4) & 1, l3 = (lam >> 3) & 1;
                const int par = (l5 & l4) + (l4 & w1) + (w1 & w0) + __popc(lam & (lam >> 1) & 0x7);
                const float base = (par & 1) ? -1.0f : 1.0f;
                const float fA = l5 ? -1.0f : 1.0f;
                const float fB = w0 ? -1.0f : 1.0f;
                const float fC = l3 ? -1.0f : 1.0f;
#pragma unroll
                for (int j = 0; j < 16; ++j) {
                    float s = base;
                    if (j & 4) s *= fA;
                    if (j & 2) s *= fB;
                    if (j & 1) s *= fC;
                    if ((((j & 12) == 12) ? 1 : 0) ^ (((j & 3) == 3) ? 1 : 0)) s = -s;
                    st[j] *= s;
                }
            }
            // fused RZ diagonal, row 2h+1, in L3 (beta row 2h+1, L3 form)
            apply_phase(st, dreg + (2 * h + 1) * 32,
                        *(const f2*)(btab + ((2 * h + 1) * 256 + tix) * 2));
        }
        // ============ reverse layer l = 2h+1 : L3 -> L2 -> L1 ============
        {
            const int gb = (2 * h + 1) * NQ;
            RYGATE(gb + 7, 0); RYGATE(gb + 6, 1); RYGATE(gb + 1, 2); RYGATE(gb + 0, 3);
            // T_b back (involution; prior T_b reads cross-wave -> barrier before writes)
            __syncthreads();
#pragma unroll
            for (int j = 0; j < 16; ++j) bufr[tix * RSTR + j] = st[j].x;
            __syncthreads();
#pragma unroll
            for (int j = 0; j < 16; ++j) st[j].x = bufr[TBROW(j) * RSTR + col_b];
            __syncthreads();   // drain re reads before im overwrites
#pragma unroll
            for (int j = 0; j < 16; ++j) bufr[tix * RSTR + j] = st[j].y;
            __syncthreads();
#pragma unroll
            for (int j = 0; j < 16; ++j) st[j].y = bufr[TBROW(j) * RSTR + col_b];
            RYGATE(gb + 5, 0); RYGATE(gb + 4, 1); RYGATE(gb + 3, 2); RYGATE(gb + 2, 3);
            // T_a back (prior T_b reads cross-wave -> barrier before writes; then wave-local)
            __syncthreads();
#pragma unroll
            for (int j = 0; j < 16; ++j) bufr[tix * RSTR + j] = st[j].x;
            WFENCE();
#pragma unroll
            for (int j = 0; j < 16; ++j) st[j].x = bufr[(row_a + j) * RSTR + col_a];
            WFENCE();
#pragma unroll
            for (int j = 0; j < 16; ++j) bufr[tix * RSTR + j] = st[j].y;
            WFENCE();
#pragma unroll
            for (int j = 0; j < 16; ++j) st[j].y = bufr[(row_a + j) * RSTR + col_a];
            RYGATE(gb + 11, 0); RYGATE(gb + 10, 1); RYGATE(gb + 9, 2); RYGATE(gb + 8, 3);
            if (h == 0) {
                // CZ sign in L1 (R6/R8-verified)
                {
                    const int par = __popc(lam & (lam >> 1)) + ((lam & 1) & w1) + (w1 & w0);
                    const float base = (par & 1) ? -1.0f : 1.0f;
                    const float sHi = w0 ? -base : base;
#pragma unroll
                    for (int j = 0; j < 16; ++j) {
                        float s = (j & 8) ? sHi : base;
                        if (__popc(j & (j >> 1)) & 1) s = -s;
                        st[j] *= s;
                    }
                }
                // fused RZ diagonal, row 2, in L1 (beta row 2, L1 form)
                apply_phase(st, dreg + 2 * 32, *(const f2*)(btab + (2 * 256 + tix) * 2));
            }
            // h==1: trailing diagonals dropped (probs phase-invariant)
        }
    }

    // --- measurement in L1 ---
    float tot = 0.f, m8 = 0.f, m9 = 0.f, m10 = 0.f, m11 = 0.f;
#pragma unroll
    for (int j = 0; j < 16; ++j) {
        const float p = st[j].x * st[j].x + st[j].y * st[j].y;
        tot += p;
        m8  += (j & 8) ? -p : p;
        m9  += (j & 4) ? -p : p;
        m10 += (j & 2) ? -p : p;
        m11 += (j & 1) ? -p : p;
    }

    // Walsh reduction (R14-HW-verified signs): part[q] = (lam bit (5-q)) ? -tot : +tot
    // -> spawn D = S - p (low half minus high half) at the stage crossing that bit.
    float S = tot, D5, D4, D3, D2, D1, D0, p;
    p = __shfl_down(S, 32, 64); D5 = S - p; S += p;
    p = __shfl_down(S, 16, 64); D4 = S - p; S += p;
    D5 += __shfl_down(D5, 16, 64);
    p = __shfl_down(S, 8, 64);  D3 = S - p; S += p;
    D5 += __shfl_down(D5, 8, 64); D4 += __shfl_down(D4, 8, 64);
    p = __shfl_down(S, 4, 64);  D2 = S - p; S += p;
    D5 += __shfl_down(D5, 4, 64); D4 += __shfl_down(D4, 4, 64); D3 += __shfl_down(D3, 4, 64);
    p = __shfl_down(S, 2, 64);  D1 = S - p; S += p;
    D5 += __shfl_down(D5, 2, 64); D4 += __shfl_down(D4, 2, 64); D3 += __shfl_down(D3, 2, 64);
    D2 += __shfl_down(D2, 2, 64);
    p = __shfl_down(S, 1, 64);  D0 = S - p; S += p;
    D5 += __shfl_down(D5, 1, 64); D4 += __shfl_down(D4, 1, 64); D3 += __shfl_down(D3, 1, 64);
    D2 += __shfl_down(D2, 1, 64); D1 += __shfl_down(D1, 1, 64);
#pragma unroll
    for (int off = 32; off > 0; off >>= 1) {
        m8  += __shfl_down(m8,  off, 64);
        m9  += __shfl_down(m9,  off, 64);
        m10 += __shfl_down(m10, off, 64);
        m11 += __shfl_down(m11, off, 64);
    }

    if (lam == 0) {
        red[w][0] = D5; red[w][1] = D4; red[w][2] = D3;
        red[w][3] = D2; red[w][4] = D1; red[w][5] = D0;
        red[w][6] = S;
        red[w][7] = m8; red[w][8] = m9; red[w][9] = m10; red[w][10] = m11;
    }
    __syncthreads();
    if (tix < NQ) {
        float v;
        if (tix < 6)       v = red[0][tix] + red[1][tix] + red[2][tix] + red[3][tix];
        else if (tix == 6) v = red[0][6] + red[1][6] - red[2][6] - red[3][6];  // w1 set for w>=2
        else if (tix == 7) v = red[0][6] - red[1][6] + red[2][6] - red[3][6];  // w0 set for odd w
        else { const int k = tix - 1; v = red[0][k] + red[1][k] + red[2][k] + red[3][k]; }
        qout[tix] = v;
    }
    __syncthreads();

    if (tix < NA) {
        float acc = fc_b[tix];
#pragma unroll
        for (int q = 0; q < NQ; ++q)
            acc += qout[q] * fc_w[tix * NQ + q];
        out[b * NA + tix] = acc;
    }
}

extern "C" void kernel_launch(void* const* d_in, const int* in_sizes, int n_in,
                              void* d_out, int out_size, void* d_ws, size_t ws_size,
                              hipStream_t stream) {
    const float* x   = (const float*)d_in[0];
    const float* wts = (const float*)d_in[1];
    const float* fcw = (const float*)d_in[2];
    const float* fcb = (const float*)d_in[3];
    float* tabs = (float*)d_ws;   // 2320 f32 = 9280 B (gates/alphas/dreg + beta table)
    setup_kernel<<<1, 64, 0, stream>>>(wts, tabs);
    qdqn_kernel<<<BATCH, NT, 0, stream>>>(x, tabs, fcw, fcb, (float*)d_out);
}

// Round 6
// 148.002 us; speedup vs baseline: 1.0169x; 1.0003x over previous
//
#include <hip/hip_runtime.h>
#include <math.h>

#define NQ 12
#define NL 4
#define NA 6
#define BATCH 4096
#define NT 256
#define RSTR 17   // float (b32) row stride; odd -> conflict-free at 2-dword/bank b32 floor

typedef float f2 __attribute__((ext_vector_type(2)));

// HW-verified (R3-R10) packed complex primitives; (re,im) in a VGPR pair.
#define CMUL(d, u, a)  asm("v_pk_mul_f32 %0, %1, %2 op_sel_hi:[0,1]"                 : "=v"(d) : "v"(u), "v"(a))
#define CMACR(d, u, a) asm("v_pk_fma_f32 %0, %1, %2, %0 op_sel_hi:[0,1,1]"           : "+v"(d) : "v"(u), "v"(a))
#define CMACI(d, u, a) asm("v_pk_fma_f32 %0, %1, %2, %0 op_sel:[1,1,0] op_sel_hi:[1,0,1] neg_lo:[1,0,0]" : "+v"(d) : "v"(u), "v"(a))
// R10-verified scalar-broadcast variants (coefficient f2 = (c,s)):
#define RYMULS(d, u, a)  asm("v_pk_mul_f32 %0, %1, %2 op_sel:[1,0] op_sel_hi:[1,1]"  : "=v"(d) : "v"(u), "v"(a))
#define RYMACNS(d, u, a) asm("v_pk_fma_f32 %0, %1, %2, %0 op_sel:[1,0,0] op_sel_hi:[1,1,1] neg_lo:[1,0,0] neg_hi:[1,0,0]" : "+v"(d) : "v"(u), "v"(a))
#define WFENCE() asm volatile("s_waitcnt lgkmcnt(0)" ::: "memory")

// Real RY butterfly: n0 = c*a0 - s*a1 ; n1 = s*a0 + c*a1   (4 pk ops)
#define RYBFLY(A0, A1, CS) do { \
    f2 _a0 = (A0), _a1 = (A1), _n0, _n1; \
    CMUL  (_n0, CS, _a0); RYMACNS(_n0, CS, _a1); \
    RYMULS(_n1, CS, _a0); CMACR  (_n1, CS, _a1); \
    (A0) = _n0; (A1) = _n1; } while (0)

#define RYGATE(gidx, bq) do { \
    const f2 cs = *(const f2*)(rots + (gidx) * 2); \
    const int S = 1 << (bq); \
    _Pragma("unroll") \
    for (int m = 0; m < 8; ++m) { \
        const int j0 = ((m & ~(S - 1)) << 1) | (m & (S - 1)); \
        RYBFLY(st[j0], st[j0 + S], cs); \
    } } while (0)

// Circuit algebra (R10-verified): Rot = RZ(omega)*RY(theta)*RZ(phi); diagonals folded:
// RZ(phi_0) into init; D_l = RZ(omega_l)*CZ*RZ(phi_{l+1}) between RY layers; trailing
// RZ(omega_3)+CZ_3 dropped (probs phase-invariant).
// Layouts (R8-verified): L1: i=(lam5..lam0,w1,w0,j3..j0); L2: i=(lam5,lam4,j3..j0,w1,w0,lam3..0);
// L3: i=(j3,j2,lam5,lam4,w1,w0,j1,j0,lam3..0).
// T_a (L1<->L2, involution, wave-local, b32 re/im passes over float[256][17]) — R12-verified.
// T_b (L2<->L3, involution, cross-wave, b32 re/im passes, 3-4 barriers) — R12-verified.
//   (R14 post-mortem: b64 T_b needs 16 VGPRs of temps -> crosses the 64-VGPR occupancy granule,
//    occupancy 46->29, net LOSS. b32 T_b at VGPR 48 is the keeper.)
// R15 (verified 94.6us kernel): (a) Walsh epilogue (45 shfl vs 72, part[12] deleted);
//   (b) beta-table in d_ws, apply_phase loads e^{i*beta} instead of computing it.
// R16: setup_kernel parallelized 64->256 threads (4 sincosf/thread for betas instead of 16,
//   4 waves instead of 1). R15 post-mortem: the serial beta setup added ~10us of stream-
//   critical-path latency before qdqn could launch — graded time regressed while kernel
//   time improved. qdqn_kernel is byte-identical to R15.
// d_ws float layout: [0..95] 48 gates (c,s) | [96..143] alphas[4][12] | [144..271] dreg[4][16]
//   (re,im) | [272..2319] beta table: (cos,sin) of beta_r(tix) for r=0..3, tix=0..255.
//   Rows r even use BETA_L1 form, r odd use BETA_L3 form (matching layout at application point).

__global__ void setup_kernel(const float* __restrict__ weights, float* __restrict__ ws) {
    __shared__ float alph_s[NL * NQ];
    const int t = threadIdx.x;   // 256 threads
    if (t < NL * NQ) {
        const float th = weights[t * 3 + 1];
        float s, c;
        sincosf(0.5f * th, &s, &c);
        ws[t * 2 + 0] = c; ws[t * 2 + 1] = s;
        const int r = t / NQ, q = t % NQ;
        float a;
        if (r == 0) a = 0.5f * weights[q * 3 + 0];
        else        a = 0.5f * (weights[((r - 1) * NQ + q) * 3 + 2] +
                                 weights[(r * NQ + q) * 3 + 0]);
        ws[96 + t] = a;
        alph_s[t] = a;
    }
    if (t < 64) {
        const int d = t >> 4, j = t & 15;
        int wq[4];
        if (d == 1 || d == 3) { wq[0] = 0; wq[1] = 1; wq[2] = 6; wq[3] = 7; }
        else                  { wq[0] = 8; wq[1] = 9; wq[2] = 10; wq[3] = 11; }
        float g = 0.0f;
#pragma unroll
        for (int k = 0; k < 4; ++k) {
            const int q = wq[k];
            const float a = (d == 0) ? 0.5f * weights[q * 3 + 0]
                                     : 0.5f * (weights[((d - 1) * NQ + q) * 3 + 2] +
                                               weights[(d * NQ + q) * 3 + 0]);
            g += ((j >> (3 - k)) & 1) ? a : -a;
        }
        float sg, cg;
        sincosf(g, &sg, &cg);
        ws[144 + (d * 16 + j) * 2 + 0] = cg;
        ws[144 + (d * 16 + j) * 2 + 1] = sg;
    }
    __syncthreads();
    // beta table: 4 rows x 256 thread-positions, ONE row per thread here (t = thread-position).
    // Row even -> L1 form, row odd -> L3 form.
    {
        const int lam = t & 63, wv = t >> 6;
        const int w1 = (wv >> 1) & 1, w0 = wv & 1;
#pragma unroll
        for (int r = 0; r < 4; ++r) {
            const float* al = alph_s + r * NQ;
            float beta;
            if ((r & 1) == 0) {   // BETA_L1
                beta = (((lam >> 5) & 1) ? al[0] : -al[0]) + (((lam >> 4) & 1) ? al[1] : -al[1])
                     + (((lam >> 3) & 1) ? al[2] : -al[2]) + (((lam >> 2) & 1) ? al[3] : -al[3])
                     + (((lam >> 1) & 1) ? al[4] : -al[4]) + (((lam >> 0) & 1) ? al[5] : -al[5])
                     + (w1 ? al[6] : -al[6]) + (w0 ? al[7] : -al[7]);
            } else {              // BETA_L3
                beta = (((lam >> 5) & 1) ? al[2] : -al[2]) + (((lam >> 4) & 1) ? al[3] : -al[3])
                     + (w1 ? al[4] : -al[4]) + (w0 ? al[5] : -al[5])
                     + (((lam >> 3) & 1) ? al[8] : -al[8]) + (((lam >> 2) & 1) ? al[9] : -al[9])
                     + (((lam >> 1) & 1) ? al[10] : -al[10]) + (((lam >> 0) & 1) ? al[11] : -al[11]);
            }
            float sb, cb;
            sincosf(beta, &sb, &cb);
            ws[272 + (r * 256 + t) * 2 + 0] = cb;
            ws[272 + (r * 256 + t) * 2 + 1] = sb;
        }
    }
}

// st[j] *= Dth * dreg_tab[j]   (R10-verified core; R15: Dth from beta table)
__device__ __forceinline__ void apply_phase(f2* st, const float* tab, f2 Dth) {
#pragma unroll
    for (int j = 0; j < 16; ++j) {
        const f2 a = st[j];
        f2 t, u;
        CMUL(t, Dth, a); CMACI(t, Dth, a);
        const f2 dg = *(const f2*)(tab + 2 * j);
        CMUL(u, dg, t); CMACI(u, dg, t);
        st[j] = u;
    }
}

__global__ __launch_bounds__(NT) void qdqn_kernel(
    const float* __restrict__ x,       // [BATCH,12]
    const float* __restrict__ rots,    // d_ws tables
    const float* __restrict__ fc_w,    // [6,12]
    const float* __restrict__ fc_b,    // [6]
    float* __restrict__ out)           // [BATCH,6]
{
    __shared__ __align__(16) float bufr[NT * RSTR];   // 17408 B b32 transpose buffer
    __shared__ float encc[NQ], encs[NQ];
    __shared__ float red[4][NQ];
    __shared__ float qout[NQ];

    const int tix = threadIdx.x;
    const int lam = tix & 63;
    const int w   = tix >> 6;
    const int w1  = (w >> 1) & 1, w0 = w & 1;
    const int b   = blockIdx.x;

    const float* dreg = rots + 144;
    const float* btab = rots + 272;

    if (tix < NQ) {
        float s, c;
        sincosf(0.5f * x[b * NQ + tix], &s, &c);
        encc[tix] = c; encs[tix] = s;
    }
    __syncthreads();

    // --- RY product state in L1 (real) ---
    f2 st[16];
    {
        float pre = 1.0f;
#pragma unroll
        for (int q = 0; q < 6; ++q)
            pre *= ((lam >> (5 - q)) & 1) ? encs[q] : encc[q];
        pre *= w1 ? encs[6] : encc[6];
        pre *= w0 ? encs[7] : encc[7];
        const float c8 = encc[8],  s8 = encs[8];
        const float c9 = encc[9],  s9 = encs[9];
        const float cA = encc[10], sA = encs[10];
        const float cB = encc[11], sB = encs[11];
#pragma unroll
        for (int j = 0; j < 16; ++j) {
            float v = pre;
            v *= (j & 8) ? s8 : c8;
            v *= (j & 4) ? s9 : c9;
            v *= (j & 2) ? sA : cA;
            v *= (j & 1) ? sB : cB;
            st[j] = (f2){ v, 0.0f };
        }
    }

    // --- init diagonal: RZ(phi_0) in L1 (beta row 0) ---
    apply_phase(st, dreg + 0 * 32, *(const f2*)(btab + (0 * 256 + tix) * 2));

    const int col_b = ((lam >> 4) << 2) | w;
    const int row_a = (w << 6) | (lam & 0x30);
    const int col_a = lam & 0xF;

#define TBROW(j) ((((j) & 3) << 6) | (((j) >> 2) << 4) | (lam & 15))

    // T_a (wave-local throughout: wave w only touches float-rows (w<<6)..(w<<6)+63): fences only.
#define TRANSPOSE_A_FWD() do { \
    WFENCE(); \
    _Pragma("unroll") for (int j = 0; j < 16; ++j) bufr[tix * RSTR + j] = st[j].x; \
    WFENCE(); \
    _Pragma("unroll") for (int j = 0; j < 16; ++j) st[j].x = bufr[(row_a + j) * RSTR + col_a]; \
    WFENCE(); \
    _Pragma("unroll") for (int j = 0; j < 16; ++j) bufr[tix * RSTR + j] = st[j].y; \
    WFENCE(); \
    _Pragma("unroll") for (int j = 0; j < 16; ++j) st[j].y = bufr[(row_a + j) * RSTR + col_a]; \
    } while (0)

#pragma unroll 1
    for (int h = 0; h < 2; ++h) {
        // ============ forward layer l = 2h : L1 -> L2 -> L3 ============
        {
            const int gb = (2 * h) * NQ;
            RYGATE(gb + 11, 0); RYGATE(gb + 10, 1); RYGATE(gb + 9, 2); RYGATE(gb + 8, 3);
            TRANSPOSE_A_FWD();                      // wave-local (prior readers in-wave or none)
            RYGATE(gb + 5, 0); RYGATE(gb + 4, 1); RYGATE(gb + 3, 2); RYGATE(gb + 2, 3);
            // T_b (cross-wave reads), re pass then im pass (R12-verified schedule)
            WFENCE();
#pragma unroll
            for (int j = 0; j < 16; ++j) bufr[tix * RSTR + j] = st[j].x;
            __syncthreads();
#pragma unroll
            for (int j = 0; j < 16; ++j) st[j].x = bufr[TBROW(j) * RSTR + col_b];
            __syncthreads();   // drain re reads before im overwrites
#pragma unroll
            for (int j = 0; j < 16; ++j) bufr[tix * RSTR + j] = st[j].y;
            __syncthreads();
#pragma unroll
            for (int j = 0; j < 16; ++j) st[j].y = bufr[TBROW(j) * RSTR + col_b];
            RYGATE(gb + 7, 0); RYGATE(gb + 6, 1); RYGATE(gb + 1, 2); RYGATE(gb + 0, 3);
            // CZ sign in L3 (R8-verified)
            {
                const int l5 = (lam >> 5) & 1, l4 = (lam >> 4) & 1, l3 = (lam >> 3) & 1;
                const int par = (l5 & l4) + (l4 & w1) + (w1 & w0) + __popc(lam & (lam >> 1) & 0x7);
                const float base = (par & 1) ? -1.0f : 1.0f;
                const float fA = l5 ? -1.0f : 1.0f;
                const float fB = w0 ? -1.0f : 1.0f;
                const float fC = l3 ? -1.0f : 1.0f;
#pragma unroll
                for (int j = 0; j < 16; ++j) {
                    float s = base;
                    if (j & 4) s *= fA;
                    if (j & 2) s *= fB;
                    if (j & 1) s *= fC;
                    if ((((j & 12) == 12) ? 1 : 0) ^ (((j & 3) == 3) ? 1 : 0)) s = -s;
                    st[j] *= s;
                }
            }
            // fused RZ diagonal, row 2h+1, in L3 (beta row 2h+1, L3 form)
            apply_phase(st, dreg + (2 * h + 1) * 32,
                        *(const f2*)(btab + ((2 * h + 1) * 256 + tix) * 2));
        }
        // ============ reverse layer l = 2h+1 : L3 -> L2 -> L1 ============
        {
            const int gb = (2 * h + 1) * NQ;
            RYGATE(gb + 7, 0); RYGATE(gb + 6, 1); RYGATE(gb + 1, 2); RYGATE(gb + 0, 3);
            // T_b back (involution; prior T_b reads cross-wave -> barrier before writes)
            __syncthreads();
#pragma unroll
            for (int j = 0; j < 16; ++j) bufr[tix * RSTR + j] = st[j].x;
            __syncthreads();
#pragma unroll
            for (int j = 0; j < 16; ++j) st[j].x = bufr[TBROW(j) * RSTR + col_b];
            __syncthreads();   // drain re reads before im overwrites
#pragma unroll
            for (int j = 0; j < 16; ++j) bufr[tix * RSTR + j] = st[j].y;
            __syncthreads();
#pragma unroll
            for (int j = 0; j < 16; ++j) st[j].y = bufr[TBROW(j) * RSTR + col_b];
            RYGATE(gb + 5, 0); RYGATE(gb + 4, 1); RYGATE(gb + 3, 2); RYGATE(gb + 2, 3);
            // T_a back (prior T_b reads cross-wave -> barrier before writes; then wave-local)
            __syncthreads();
#pragma unroll
            for (int j = 0; j < 16; ++j) bufr[tix * RSTR + j] = st[j].x;
            WFENCE();
#pragma unroll
            for (int j = 0; j < 16; ++j) st[j].x = bufr[(row_a + j) * RSTR + col_a];
            WFENCE();
#pragma unroll
            for (int j = 0; j < 16; ++j) bufr[tix * RSTR + j] = st[j].y;
            WFENCE();
#pragma unroll
            for (int j = 0; j < 16; ++j) st[j].y = bufr[(row_a + j) * RSTR + col_a];
            RYGATE(gb + 11, 0); RYGATE(gb + 10, 1); RYGATE(gb + 9, 2); RYGATE(gb + 8, 3);
            if (h == 0) {
                // CZ sign in L1 (R6/R8-verified)
                {
                    const int par = __popc(lam & (lam >> 1)) + ((lam & 1) & w1) + (w1 & w0);
                    const float base = (par & 1) ? -1.0f : 1.0f;
                    const float sHi = w0 ? -base : base;
#pragma unroll
                    for (int j = 0; j < 16; ++j) {
                        float s = (j & 8) ? sHi : base;
                        if (__popc(j & (j >> 1)) & 1) s = -s;
                        st[j] *= s;
                    }
                }
                // fused RZ diagonal, row 2, in L1 (beta row 2, L1 form)
                apply_phase(st, dreg + 2 * 32, *(const f2*)(btab + (2 * 256 + tix) * 2));
            }
            // h==1: trailing diagonals dropped (probs phase-invariant)
        }
    }

    // --- measurement in L1 ---
    float tot = 0.f, m8 = 0.f, m9 = 0.f, m10 = 0.f, m11 = 0.f;
#pragma unroll
    for (int j = 0; j < 16; ++j) {
        const float p = st[j].x * st[j].x + st[j].y * st[j].y;
        tot += p;
        m8  += (j & 8) ? -p : p;
        m9  += (j & 4) ? -p : p;
        m10 += (j & 2) ? -p : p;
        m11 += (j & 1) ? -p : p;
    }

    // Walsh reduction (R14-HW-verified signs): part[q] = (lam bit (5-q)) ? -tot : +tot
    // -> spawn D = S - p (low half minus high half) at the stage crossing that bit.
    float S = tot, D5, D4, D3, D2, D1, D0, p;
    p = __shfl_down(S, 32, 64); D5 = S - p; S += p;
    p = __shfl_down(S, 16, 64); D4 = S - p; S += p;
    D5 += __shfl_down(D5, 16, 64);
    p = __shfl_down(S, 8, 64);  D3 = S - p; S += p;
    D5 += __shfl_down(D5, 8, 64); D4 += __shfl_down(D4, 8, 64);
    p = __shfl_down(S, 4, 64);  D2 = S - p; S += p;
    D5 += __shfl_down(D5, 4, 64); D4 += __shfl_down(D4, 4, 64); D3 += __shfl_down(D3, 4, 64);
    p = __shfl_down(S, 2, 64);  D1 = S - p; S += p;
    D5 += __shfl_down(D5, 2, 64); D4 += __shfl_down(D4, 2, 64); D3 += __shfl_down(D3, 2, 64);
    D2 += __shfl_down(D2, 2, 64);
    p = __shfl_down(S, 1, 64);  D0 = S - p; S += p;
    D5 += __shfl_down(D5, 1, 64); D4 += __shfl_down(D4, 1, 64); D3 += __shfl_down(D3, 1, 64);
    D2 += __shfl_down(D2, 1, 64); D1 += __shfl_down(D1, 1, 64);
#pragma unroll
    for (int off = 32; off > 0; off >>= 1) {
        m8  += __shfl_down(m8,  off, 64);
        m9  += __shfl_down(m9,  off, 64);
        m10 += __shfl_down(m10, off, 64);
        m11 += __shfl_down(m11, off, 64);
    }

    if (lam == 0) {
        red[w][0] = D5; red[w][1] = D4; red[w][2] = D3;
        red[w][3] = D2; red[w][4] = D1; red[w][5] = D0;
        red[w][6] = S;
        red[w][7] = m8; red[w][8] = m9; red[w][9] = m10; red[w][10] = m11;
    }
    __syncthreads();
    if (tix < NQ) {
        float v;
        if (tix < 6)       v = red[0][tix] + red[1][tix] + red[2][tix] + red[3][tix];
        else if (tix == 6) v = red[0][6] + red[1][6] - red[2][6] - red[3][6];  // w1 set for w>=2
        else if (tix == 7) v = red[0][6] - red[1][6] + red[2][6] - red[3][6];  // w0 set for odd w
        else { const int k = tix - 1; v = red[0][k] + red[1][k] + red[2][k] + red[3][k]; }
        qout[tix] = v;
    }
    __syncthreads();

    if (tix < NA) {
        float acc = fc_b[tix];
#pragma unroll
        for (int q = 0; q < NQ; ++q)
            acc += qout[q] * fc_w[tix * NQ + q];
        out[b * NA + tix] = acc;
    }
}

extern "C" void kernel_launch(void* const* d_in, const int* in_sizes, int n_in,
                              void* d_out, int out_size, void* d_ws, size_t ws_size,
                              hipStream_t stream) {
    const float* x   = (const float*)d_in[0];
    const float* wts = (const float*)d_in[1];
    const float* fcw = (const float*)d_in[2];
    const float* fcb = (const float*)d_in[3];
    float* tabs = (float*)d_ws;   // 2320 f32 = 9280 B (gates/alphas/dreg + beta table)
    setup_kernel<<<1, 256, 0, stream>>>(wts, tabs);
    qdqn_kernel<<<BATCH, NT, 0, stream>>>(x, tabs, fcw, fcb, (float*)d_out);
}